// Round 1
// baseline (294.197 us; speedup 1.0000x reference)
//
#include <hip/hip_runtime.h>

// SSIM fused, round 6: kill the scratch spills, double the occupancy.
//  - Round 5 evidence: WRITE_SIZE=41.5 MB (kernel writes only 4 KB of
//    partials) == per-thread spill footprint; VGPR_Count=128 despite the
//    waves_per_eu(2,2) pin; occupancy grid-capped at 2 blocks/CU. The ring
//    (5 q x 4 cols x 7 = 140 floats) + temps ~200 regs > 128 -> ~70
//    floats/thread round-tripping through scratch every STEP.
//  - Fix: 2 cols/lane (float2 loads). Ring = 5 x 2 x 7 = 70 floats; total
//    live state ~113 VGPRs -> genuinely fits 128, zero spills.
//  - Halo: 6 bpermute floats per image from lanes +1,+2,+3 (both halves).
//    Wave covers 122 productive cols (61/64 lanes, same waste as before).
//  - Grid: 4 x 16 x 16 = 1024 blocks = 4 blocks/CU = 4 waves/EU -> 2x the
//    latency hiding, exactly the occupancy the 128-VGPR budget allows.
// Geometry: 16 x 1 x 1080 x 1920 fp32; VALID 7x7 -> 16 x 1074 x 1914.

constexpr int W_IN = 1920, H_IN = 1080;
constexpr int WOUT = W_IN - 6;    // 1914
constexpr int HOUT = H_IN - 6;    // 1074
constexpr int NBATCH = 16;
constexpr int WCOLS = 122;        // productive cols per wave (61 lanes x 2)
constexpr int TW = 4 * WCOLS;     // 488 cols per block
constexpr int TH = 71;            // output rows per y-tile (NITER = 77 = 7*11)
constexpr int NBX = 4, NBY = 16;  // 4*488>=1914(+pad), 16*71>=1074
constexpr int NBLK = NBX * NBY * NBATCH;  // 1024 = exactly 4 per CU

constexpr float C1f = 6.5025f;    // (0.01*255)^2
constexpr float C2f = 58.5225f;   // (0.03*255)^2
constexpr float INV49 = 1.0f / 49.0f;

__device__ __forceinline__ float bperm(int addr, float v) {
  return __int_as_float(__builtin_amdgcn_ds_bpermute(addr, __float_as_int(v)));
}

__global__ __attribute__((amdgpu_flat_work_group_size(256, 256),
                          amdgpu_waves_per_eu(4)))
void ssim_kernel(const float* __restrict__ img1, const float* __restrict__ img2,
                 double* __restrict__ partial) {
  const int t = threadIdx.x;
  const int lane = t & 63;
  const int xw = blockIdx.x * TW + (t >> 6) * WCOLS;  // wave col base
  const int y0 = blockIdx.y * TH;
  const size_t ib = (size_t)blockIdx.z * (size_t)(H_IN * W_IN);
  const float* __restrict__ p1 = img1 + ib;
  const float* __restrict__ p2 = img2 + ib;

  // gcol is always even (xw even, 2*lane even) -> the W_IN-2 clamp can only
  // hit non-productive/halo-irrelevant lanes (parity argument: the last
  // productive window, col 1913, is always a c1, whose c0+7 halo float is
  // lane+3's .y at cols (1918,1919) -> unclamped).
  const int gcol = min(xw + 2 * lane, W_IN - 2);  // clamped, 8B-aligned
  const int up1 = ((lane + 1) & 63) << 2;         // bpermute byte addrs
  const int up2 = ((lane + 2) & 63) << 2;
  const int up3 = ((lane + 3) & 63) << 2;
  const bool lv = lane < 61;
  const bool m0 = lv && (xw + 2 * lane + 0 < WOUT);
  const bool m1 = lv && (xw + 2 * lane + 1 < WOUT);

  // thread-private rowsum ring: 5 quantities x 2 cols x 7 slots (named)
#define DECLR(Q, C)                                                          \
  float R##Q##_##C##_0 = 0.f, R##Q##_##C##_1 = 0.f, R##Q##_##C##_2 = 0.f,    \
        R##Q##_##C##_3 = 0.f, R##Q##_##C##_4 = 0.f, R##Q##_##C##_5 = 0.f,    \
        R##Q##_##C##_6 = 0.f;
  DECLR(1, 0) DECLR(1, 1)
  DECLR(2, 0) DECLR(2, 1)
  DECLR(3, 0) DECLR(3, 1)   // 3 = a*a
  DECLR(4, 0) DECLR(4, 1)   // 4 = b*b
  DECLR(5, 0) DECLR(5, 1)   // 5 = a*b
#undef DECLR
#define DECLV(Q) float V##Q##_0 = 0.f, V##Q##_1 = 0.f;
  DECLV(1) DECLV(2) DECLV(3) DECLV(4) DECLV(5)
#undef DECLV

  float accv = 0.f;

  // prologue: row y0 -> A registers (y0 <= 1065, no clamp needed)
  float2 Aa = *(const float2*)(p1 + (size_t)y0 * W_IN + gcol);
  float2 Ab = *(const float2*)(p2 + (size_t)y0 * W_IN + gcol);
  float2 Ba, Bb;
  int gyn = y0 + 1;   // next input row to load (block-uniform -> SALU)
  int oy = y0;        // output row counter

#define QC(Q, C, J)                                                         \
  { V##Q##_##C += s - R##Q##_##C##_##J; R##Q##_##C##_##J = s; }

#define EPI1(VA, VB, VAA, VBB, VAB, MASK)                                   \
  {                                                                         \
    const float mu1 = (VA) * INV49, mu2 = (VB) * INV49;                     \
    const float mu1s = mu1 * mu1, mu2s = mu2 * mu2, mu12 = mu1 * mu2;       \
    const float sg1 = fmaf((VAA), INV49, -mu1s);                            \
    const float sg2 = fmaf((VBB), INV49, -mu2s);                            \
    const float sg12 = fmaf((VAB), INV49, -mu12);                           \
    const float v1 = fmaf(2.f, sg12, C2f);                                  \
    const float v2 = sg1 + sg2 + C2f;                                       \
    const float num = fmaf(2.f, mu12, C1f) * v1;                            \
    const float den = (mu1s + mu2s + C1f) * v2;                             \
    const float ss = num * __builtin_amdgcn_rcpf(den);                      \
    accv += (MASK) ? ss : 0.f;                                              \
  }

  // One input row k: CA holds row k (both imgs); NA receives row k+1
  // (issued first for latency cover); halo via bpermute; ring-slide; EPI.
  // Window cols for c0: CAa.x(c0) CAa.y(+1) a1x(+2) a1y(+3) a2x(+4)
  //                     a2y(+5) a3x(+6);  c1 slides: -CAa.x +a3y(+7).
#define STEP(J, CAa, CAb, NAa, NAb, DO_EPI)                                 \
  {                                                                         \
    NAa = *(const float2*)(p1 + (size_t)gyn * W_IN + gcol);                 \
    NAb = *(const float2*)(p2 + (size_t)gyn * W_IN + gcol);                 \
    gyn = min(gyn + 1, H_IN - 1);                                           \
    const float a1x = bperm(up1, CAa.x), a1y = bperm(up1, CAa.y);           \
    const float a2x = bperm(up2, CAa.x), a2y = bperm(up2, CAa.y);           \
    const float a3x = bperm(up3, CAa.x), a3y = bperm(up3, CAa.y);           \
    const float b1x = bperm(up1, CAb.x), b1y = bperm(up1, CAb.y);           \
    const float b2x = bperm(up2, CAb.x), b2y = bperm(up2, CAb.y);           \
    const float b3x = bperm(up3, CAb.x), b3y = bperm(up3, CAb.y);           \
    float s;                                                                \
    s = ((CAa.x + CAa.y) + (a1x + a1y)) + ((a2x + a2y) + a3x);              \
    QC(1, 0, J)                                                             \
    s = s - CAa.x + a3y;  QC(1, 1, J)                                       \
    s = ((CAb.x + CAb.y) + (b1x + b1y)) + ((b2x + b2y) + b3x);              \
    QC(2, 0, J)                                                             \
    s = s - CAb.x + b3y;  QC(2, 1, J)                                       \
    s = CAa.x * CAa.x;                                                      \
    s = fmaf(CAa.y, CAa.y, s); s = fmaf(a1x, a1x, s);                       \
    s = fmaf(a1y, a1y, s); s = fmaf(a2x, a2x, s);                           \
    s = fmaf(a2y, a2y, s); s = fmaf(a3x, a3x, s);                           \
    QC(3, 0, J)                                                             \
    s = fmaf(-CAa.x, CAa.x, fmaf(a3y, a3y, s));  QC(3, 1, J)                \
    s = CAb.x * CAb.x;                                                      \
    s = fmaf(CAb.y, CAb.y, s); s = fmaf(b1x, b1x, s);                       \
    s = fmaf(b1y, b1y, s); s = fmaf(b2x, b2x, s);                           \
    s = fmaf(b2y, b2y, s); s = fmaf(b3x, b3x, s);                           \
    QC(4, 0, J)                                                             \
    s = fmaf(-CAb.x, CAb.x, fmaf(b3y, b3y, s));  QC(4, 1, J)                \
    s = CAa.x * CAb.x;                                                      \
    s = fmaf(CAa.y, CAb.y, s); s = fmaf(a1x, b1x, s);                       \
    s = fmaf(a1y, b1y, s); s = fmaf(a2x, b2x, s);                           \
    s = fmaf(a2y, b2y, s); s = fmaf(a3x, b3x, s);                           \
    QC(5, 0, J)                                                             \
    s = fmaf(-CAa.x, CAb.x, fmaf(a3y, b3y, s));  QC(5, 1, J)                \
    if (DO_EPI) {                                                           \
      if (oy < HOUT) {                                                      \
        EPI1(V1_0, V2_0, V3_0, V4_0, V5_0, m0)                              \
        EPI1(V1_1, V2_1, V3_1, V4_1, V5_1, m1)                              \
      }                                                                     \
      ++oy;                                                                 \
    }                                                                       \
  }

  // warm-up group: rows 0..6 (row k consumed from A if k even, B if odd)
  STEP(0, Aa, Ab, Ba, Bb, false)
  STEP(1, Ba, Bb, Aa, Ab, false)
  STEP(2, Aa, Ab, Ba, Bb, false)
  STEP(3, Ba, Bb, Aa, Ab, false)
  STEP(4, Aa, Ab, Ba, Bb, false)
  STEP(5, Ba, Bb, Aa, Ab, false)
  STEP(6, Aa, Ab, Ba, Bb, true)
  // 5 x (odd-start group + even-start group): rows 7..76
  for (int gp = 0; gp < 5; ++gp) {
    STEP(0, Ba, Bb, Aa, Ab, true)
    STEP(1, Aa, Ab, Ba, Bb, true)
    STEP(2, Ba, Bb, Aa, Ab, true)
    STEP(3, Aa, Ab, Ba, Bb, true)
    STEP(4, Ba, Bb, Aa, Ab, true)
    STEP(5, Aa, Ab, Ba, Bb, true)
    STEP(6, Ba, Bb, Aa, Ab, true)
    STEP(0, Aa, Ab, Ba, Bb, true)
    STEP(1, Ba, Bb, Aa, Ab, true)
    STEP(2, Aa, Ab, Ba, Bb, true)
    STEP(3, Ba, Bb, Aa, Ab, true)
    STEP(4, Aa, Ab, Ba, Bb, true)
    STEP(5, Ba, Bb, Aa, Ab, true)
    STEP(6, Aa, Ab, Ba, Bb, true)
  }
#undef STEP
#undef QC
#undef EPI1

  // block reduction: 64-wide shuffle -> LDS -> one double per block
  __shared__ float wsum[4];
#pragma unroll
  for (int off = 32; off > 0; off >>= 1) accv += __shfl_down(accv, off);
  if ((t & 63) == 0) wsum[t >> 6] = accv;
  __syncthreads();
  if (t == 0) {
    const int bid = blockIdx.x + NBX * (blockIdx.y + NBY * blockIdx.z);
    partial[bid] = (double)wsum[0] + (double)wsum[1] +
                   (double)wsum[2] + (double)wsum[3];
  }
}

__global__ __launch_bounds__(256)
void finalize_kernel(const double* __restrict__ partial,
                     float* __restrict__ out) {
  const int tid = threadIdx.x;
  double s = 0.0;
  for (int i = tid; i < NBLK; i += 256) s += partial[i];
#pragma unroll
  for (int off = 32; off > 0; off >>= 1) s += __shfl_down(s, off);
  __shared__ double ws[4];
  if ((tid & 63) == 0) ws[tid >> 6] = s;
  __syncthreads();
  if (tid == 0) {
    const double tot = ws[0] + ws[1] + ws[2] + ws[3];
    out[0] = (float)(tot / ((double)NBATCH * (double)HOUT * (double)WOUT));
  }
}

extern "C" void kernel_launch(void* const* d_in, const int* in_sizes, int n_in,
                              void* d_out, int out_size, void* d_ws, size_t ws_size,
                              hipStream_t stream) {
  const float* img1 = (const float*)d_in[0];
  const float* img2 = (const float*)d_in[1];
  // d_in[2] is the uniform 1/49 window -- baked into INV49.
  double* partial = (double*)d_ws;  // NBLK doubles, every slot written
  dim3 grid(NBX, NBY, NBATCH);      // 4 x 16 x 16 = 1024 blocks
  hipLaunchKernelGGL(ssim_kernel, grid, dim3(256), 0, stream, img1, img2,
                     partial);
  hipLaunchKernelGGL(finalize_kernel, dim3(1), dim3(256), 0, stream, partial,
                     (float*)d_out);
}

// Round 2
// 292.342 us; speedup vs baseline: 1.0063x; 1.0063x over previous
//
#include <hip/hip_runtime.h>

// SSIM fused, round 7: pin the VGPR budget (waves_per_eu(4,4)).
//  - Round 6 evidence: with waves_per_eu(4) [min only], the allocator aimed
//    at the NEXT occupancy step (8 waves/EU -> 64-VGPR budget), reported
//    VGPR_Count=64, and spilled the 70-float ring again: WRITE_SIZE=72.6 MB
//    of scratch vs 4 KB of real output. Occupancy doubled (20->40%) which
//    is why dur held ~121 us despite the spills.
//  - Live state of the 2-col variant is ~112 VGPRs (ring 70 + V 10 + acc 1
//    + 8 load regs + 12 bpermute temps + addr/masks ~10): fits 128, not 64.
//  - Fix: amdgpu_waves_per_eu(4,4) pins min=max=4 waves/EU -> exactly the
//    2048/4 = 128-reg budget; allocator has no incentive to shrink to 64.
//    Grid already saturates that occupancy: 1024 blocks = 4/CU = 16 waves/CU.
// Geometry: 16 x 1 x 1080 x 1920 fp32; VALID 7x7 -> 16 x 1074 x 1914.

constexpr int W_IN = 1920, H_IN = 1080;
constexpr int WOUT = W_IN - 6;    // 1914
constexpr int HOUT = H_IN - 6;    // 1074
constexpr int NBATCH = 16;
constexpr int WCOLS = 122;        // productive cols per wave (61 lanes x 2)
constexpr int TW = 4 * WCOLS;     // 488 cols per block
constexpr int TH = 71;            // output rows per y-tile (NITER = 77 = 7*11)
constexpr int NBX = 4, NBY = 16;  // 4*488>=1914(+pad), 16*71>=1074
constexpr int NBLK = NBX * NBY * NBATCH;  // 1024 = exactly 4 per CU

constexpr float C1f = 6.5025f;    // (0.01*255)^2
constexpr float C2f = 58.5225f;   // (0.03*255)^2
constexpr float INV49 = 1.0f / 49.0f;

__device__ __forceinline__ float bperm(int addr, float v) {
  return __int_as_float(__builtin_amdgcn_ds_bpermute(addr, __float_as_int(v)));
}

__global__ __attribute__((amdgpu_flat_work_group_size(256, 256),
                          amdgpu_waves_per_eu(4, 4)))
void ssim_kernel(const float* __restrict__ img1, const float* __restrict__ img2,
                 double* __restrict__ partial) {
  const int t = threadIdx.x;
  const int lane = t & 63;
  const int xw = blockIdx.x * TW + (t >> 6) * WCOLS;  // wave col base
  const int y0 = blockIdx.y * TH;
  const size_t ib = (size_t)blockIdx.z * (size_t)(H_IN * W_IN);
  const float* __restrict__ p1 = img1 + ib;
  const float* __restrict__ p2 = img2 + ib;

  // gcol is always even (xw even, 2*lane even) -> the W_IN-2 clamp can only
  // hit non-productive/halo-irrelevant lanes (parity argument: the last
  // productive window, col 1913, is always a c1, whose c0+7 halo float is
  // lane+3's .y at cols (1918,1919) -> unclamped).
  const int gcol = min(xw + 2 * lane, W_IN - 2);  // clamped, 8B-aligned
  const int up1 = ((lane + 1) & 63) << 2;         // bpermute byte addrs
  const int up2 = ((lane + 2) & 63) << 2;
  const int up3 = ((lane + 3) & 63) << 2;
  const bool lv = lane < 61;
  const bool m0 = lv && (xw + 2 * lane + 0 < WOUT);
  const bool m1 = lv && (xw + 2 * lane + 1 < WOUT);

  // thread-private rowsum ring: 5 quantities x 2 cols x 7 slots (named)
#define DECLR(Q, C)                                                          \
  float R##Q##_##C##_0 = 0.f, R##Q##_##C##_1 = 0.f, R##Q##_##C##_2 = 0.f,    \
        R##Q##_##C##_3 = 0.f, R##Q##_##C##_4 = 0.f, R##Q##_##C##_5 = 0.f,    \
        R##Q##_##C##_6 = 0.f;
  DECLR(1, 0) DECLR(1, 1)
  DECLR(2, 0) DECLR(2, 1)
  DECLR(3, 0) DECLR(3, 1)   // 3 = a*a
  DECLR(4, 0) DECLR(4, 1)   // 4 = b*b
  DECLR(5, 0) DECLR(5, 1)   // 5 = a*b
#undef DECLR
#define DECLV(Q) float V##Q##_0 = 0.f, V##Q##_1 = 0.f;
  DECLV(1) DECLV(2) DECLV(3) DECLV(4) DECLV(5)
#undef DECLV

  float accv = 0.f;

  // prologue: row y0 -> A registers (y0 <= 1065, no clamp needed)
  float2 Aa = *(const float2*)(p1 + (size_t)y0 * W_IN + gcol);
  float2 Ab = *(const float2*)(p2 + (size_t)y0 * W_IN + gcol);
  float2 Ba, Bb;
  int gyn = y0 + 1;   // next input row to load (block-uniform -> SALU)
  int oy = y0;        // output row counter

#define QC(Q, C, J)                                                         \
  { V##Q##_##C += s - R##Q##_##C##_##J; R##Q##_##C##_##J = s; }

#define EPI1(VA, VB, VAA, VBB, VAB, MASK)                                   \
  {                                                                         \
    const float mu1 = (VA) * INV49, mu2 = (VB) * INV49;                     \
    const float mu1s = mu1 * mu1, mu2s = mu2 * mu2, mu12 = mu1 * mu2;       \
    const float sg1 = fmaf((VAA), INV49, -mu1s);                            \
    const float sg2 = fmaf((VBB), INV49, -mu2s);                            \
    const float sg12 = fmaf((VAB), INV49, -mu12);                           \
    const float v1 = fmaf(2.f, sg12, C2f);                                  \
    const float v2 = sg1 + sg2 + C2f;                                       \
    const float num = fmaf(2.f, mu12, C1f) * v1;                            \
    const float den = (mu1s + mu2s + C1f) * v2;                             \
    const float ss = num * __builtin_amdgcn_rcpf(den);                      \
    accv += (MASK) ? ss : 0.f;                                              \
  }

  // One input row k: CA holds row k (both imgs); NA receives row k+1
  // (issued first for latency cover); halo via bpermute; ring-slide; EPI.
  // Window cols for c0: CAa.x(c0) CAa.y(+1) a1x(+2) a1y(+3) a2x(+4)
  //                     a2y(+5) a3x(+6);  c1 slides: -CAa.x +a3y(+7).
#define STEP(J, CAa, CAb, NAa, NAb, DO_EPI)                                 \
  {                                                                         \
    NAa = *(const float2*)(p1 + (size_t)gyn * W_IN + gcol);                 \
    NAb = *(const float2*)(p2 + (size_t)gyn * W_IN + gcol);                 \
    gyn = min(gyn + 1, H_IN - 1);                                           \
    const float a1x = bperm(up1, CAa.x), a1y = bperm(up1, CAa.y);           \
    const float a2x = bperm(up2, CAa.x), a2y = bperm(up2, CAa.y);           \
    const float a3x = bperm(up3, CAa.x), a3y = bperm(up3, CAa.y);           \
    const float b1x = bperm(up1, CAb.x), b1y = bperm(up1, CAb.y);           \
    const float b2x = bperm(up2, CAb.x), b2y = bperm(up2, CAb.y);           \
    const float b3x = bperm(up3, CAb.x), b3y = bperm(up3, CAb.y);           \
    float s;                                                                \
    s = ((CAa.x + CAa.y) + (a1x + a1y)) + ((a2x + a2y) + a3x);              \
    QC(1, 0, J)                                                             \
    s = s - CAa.x + a3y;  QC(1, 1, J)                                       \
    s = ((CAb.x + CAb.y) + (b1x + b1y)) + ((b2x + b2y) + b3x);              \
    QC(2, 0, J)                                                             \
    s = s - CAb.x + b3y;  QC(2, 1, J)                                       \
    s = CAa.x * CAa.x;                                                      \
    s = fmaf(CAa.y, CAa.y, s); s = fmaf(a1x, a1x, s);                       \
    s = fmaf(a1y, a1y, s); s = fmaf(a2x, a2x, s);                           \
    s = fmaf(a2y, a2y, s); s = fmaf(a3x, a3x, s);                           \
    QC(3, 0, J)                                                             \
    s = fmaf(-CAa.x, CAa.x, fmaf(a3y, a3y, s));  QC(3, 1, J)                \
    s = CAb.x * CAb.x;                                                      \
    s = fmaf(CAb.y, CAb.y, s); s = fmaf(b1x, b1x, s);                       \
    s = fmaf(b1y, b1y, s); s = fmaf(b2x, b2x, s);                           \
    s = fmaf(b2y, b2y, s); s = fmaf(b3x, b3x, s);                           \
    QC(4, 0, J)                                                             \
    s = fmaf(-CAb.x, CAb.x, fmaf(b3y, b3y, s));  QC(4, 1, J)                \
    s = CAa.x * CAb.x;                                                      \
    s = fmaf(CAa.y, CAb.y, s); s = fmaf(a1x, b1x, s);                       \
    s = fmaf(a1y, b1y, s); s = fmaf(a2x, b2x, s);                           \
    s = fmaf(a2y, b2y, s); s = fmaf(a3x, b3x, s);                           \
    QC(5, 0, J)                                                             \
    s = fmaf(-CAa.x, CAb.x, fmaf(a3y, b3y, s));  QC(5, 1, J)                \
    if (DO_EPI) {                                                           \
      if (oy < HOUT) {                                                      \
        EPI1(V1_0, V2_0, V3_0, V4_0, V5_0, m0)                              \
        EPI1(V1_1, V2_1, V3_1, V4_1, V5_1, m1)                              \
      }                                                                     \
      ++oy;                                                                 \
    }                                                                       \
  }

  // warm-up group: rows 0..6 (row k consumed from A if k even, B if odd)
  STEP(0, Aa, Ab, Ba, Bb, false)
  STEP(1, Ba, Bb, Aa, Ab, false)
  STEP(2, Aa, Ab, Ba, Bb, false)
  STEP(3, Ba, Bb, Aa, Ab, false)
  STEP(4, Aa, Ab, Ba, Bb, false)
  STEP(5, Ba, Bb, Aa, Ab, false)
  STEP(6, Aa, Ab, Ba, Bb, true)
  // 5 x (odd-start group + even-start group): rows 7..76
  for (int gp = 0; gp < 5; ++gp) {
    STEP(0, Ba, Bb, Aa, Ab, true)
    STEP(1, Aa, Ab, Ba, Bb, true)
    STEP(2, Ba, Bb, Aa, Ab, true)
    STEP(3, Aa, Ab, Ba, Bb, true)
    STEP(4, Ba, Bb, Aa, Ab, true)
    STEP(5, Aa, Ab, Ba, Bb, true)
    STEP(6, Ba, Bb, Aa, Ab, true)
    STEP(0, Aa, Ab, Ba, Bb, true)
    STEP(1, Ba, Bb, Aa, Ab, true)
    STEP(2, Aa, Ab, Ba, Bb, true)
    STEP(3, Ba, Bb, Aa, Ab, true)
    STEP(4, Aa, Ab, Ba, Bb, true)
    STEP(5, Ba, Bb, Aa, Ab, true)
    STEP(6, Aa, Ab, Ba, Bb, true)
  }
#undef STEP
#undef QC
#undef EPI1

  // block reduction: 64-wide shuffle -> LDS -> one double per block
  __shared__ float wsum[4];
#pragma unroll
  for (int off = 32; off > 0; off >>= 1) accv += __shfl_down(accv, off);
  if ((t & 63) == 0) wsum[t >> 6] = accv;
  __syncthreads();
  if (t == 0) {
    const int bid = blockIdx.x + NBX * (blockIdx.y + NBY * blockIdx.z);
    partial[bid] = (double)wsum[0] + (double)wsum[1] +
                   (double)wsum[2] + (double)wsum[3];
  }
}

__global__ __launch_bounds__(256)
void finalize_kernel(const double* __restrict__ partial,
                     float* __restrict__ out) {
  const int tid = threadIdx.x;
  double s = 0.0;
  for (int i = tid; i < NBLK; i += 256) s += partial[i];
#pragma unroll
  for (int off = 32; off > 0; off >>= 1) s += __shfl_down(s, off);
  __shared__ double ws[4];
  if ((tid & 63) == 0) ws[tid >> 6] = s;
  __syncthreads();
  if (tid == 0) {
    const double tot = ws[0] + ws[1] + ws[2] + ws[3];
    out[0] = (float)(tot / ((double)NBATCH * (double)HOUT * (double)WOUT));
  }
}

extern "C" void kernel_launch(void* const* d_in, const int* in_sizes, int n_in,
                              void* d_out, int out_size, void* d_ws, size_t ws_size,
                              hipStream_t stream) {
  const float* img1 = (const float*)d_in[0];
  const float* img2 = (const float*)d_in[1];
  // d_in[2] is the uniform 1/49 window -- baked into INV49.
  double* partial = (double*)d_ws;  // NBLK doubles, every slot written
  dim3 grid(NBX, NBY, NBATCH);      // 4 x 16 x 16 = 1024 blocks
  hipLaunchKernelGGL(ssim_kernel, grid, dim3(256), 0, stream, img1, img2,
                     partial);
  hipLaunchKernelGGL(finalize_kernel, dim3(1), dim3(256), 0, stream, partial,
                     (float*)d_out);
}